// Round 2
// baseline (8701.835 us; speedup 1.0000x reference)
//
#include <hip/hip_runtime.h>

// RNN: h_t = tanh(W_hh h_{t-1} + b_hh + W_xh emb[X_t] + b_xh)
// N=64, L=2048, V=32000, H=512.  Output (N,L,H) fp32 = 256 MB.
//
// K1: Xh' = emb[X] @ W_xh^T + b_xh + b_hh  (fp16 MFMA, fp32 accum) -> written INTO d_out.
// K2 (rewritten): NO inter-WG communication. 32 WGs x 512 thr; WG b owns batch rows
//     {2b,2b+1} and ALL 512 output cols. Full W_hh resident per CU: per wave (64 cols),
//     col-tiles 0..2 as MFMA A-frags in VGPRs (48 x half8 = 192 regs), col-tile 3 in
//     LDS (128 KB, pre-formatted frags, stride-1). h double-buffered in 4 KB LDS,
//     one __syncthreads per step.

typedef _Float16 half8 __attribute__((ext_vector_type(8)));
typedef float    f32x4 __attribute__((ext_vector_type(4)));

#define MFMA_F16(A,B,C) __builtin_amdgcn_mfma_f32_16x16x32_f16(A,B,C,0,0,0)

static __device__ __forceinline__ half8 cvt8(const float* p){
  const f32x4* q = (const f32x4*)p;
  f32x4 a = q[0], b = q[1];
  half8 r;
  r[0]=(_Float16)a[0]; r[1]=(_Float16)a[1]; r[2]=(_Float16)a[2]; r[3]=(_Float16)a[3];
  r[4]=(_Float16)b[0]; r[5]=(_Float16)b[1]; r[6]=(_Float16)b[2]; r[7]=(_Float16)b[3];
  return r;
}

static __device__ __forceinline__ float tanh_fast(float z){
  float e = __expf(2.0f*z);
  return 1.0f - 2.0f/(e + 1.0f);
}

// ---------------- Kernel 1: Xh' = E @ Wxh^T + (bxh + bhh) -> d_out ----------------
__global__ __launch_bounds__(256) void k_xh(
    const int* __restrict__ X, const float* __restrict__ emb,
    const float* __restrict__ Wxh, const float* __restrict__ bxh,
    const float* __restrict__ bhh, float* __restrict__ out)
{
  const int bid = blockIdx.x;
  const int bm = bid >> 3;
  const int bn = bid & 7;
  const int tid = threadIdx.x;
  const int w  = tid >> 6;
  const int l  = tid & 63;
  const int lr = l & 15, lq = l >> 4;

  const int mbase = bm*64 + (w>>1)*32;
  const int nbase = bn*64 + (w&1)*32;

  const int tok0 = X[mbase + lr];
  const int tok1 = X[mbase + 16 + lr];
  const int c0 = nbase + lr;
  const int c1 = nbase + 16 + lr;
  const float bs0 = bxh[c0] + bhh[c0];
  const float bs1 = bxh[c1] + bhh[c1];

  const float* a0 = emb + (long long)tok0*512 + lq*8;
  const float* a1 = emb + (long long)tok1*512 + lq*8;
  const float* b0 = Wxh + (long long)c0*512 + lq*8;
  const float* b1 = Wxh + (long long)c1*512 + lq*8;

  f32x4 acc00 = {0,0,0,0}, acc01 = {0,0,0,0}, acc10 = {0,0,0,0}, acc11 = {0,0,0,0};

  #pragma unroll
  for (int ks=0; ks<16; ++ks){
    half8 A0 = cvt8(a0 + ks*32);
    half8 A1 = cvt8(a1 + ks*32);
    half8 B0 = cvt8(b0 + ks*32);
    half8 B1 = cvt8(b1 + ks*32);
    acc00 = MFMA_F16(A0, B0, acc00);
    acc01 = MFMA_F16(A0, B1, acc01);
    acc10 = MFMA_F16(A1, B0, acc10);
    acc11 = MFMA_F16(A1, B1, acc11);
  }
  #pragma unroll
  for (int r=0; r<4; ++r){
    const long long m0 = mbase + 4*lq + r;
    const long long m1 = m0 + 16;
    out[m0*512 + c0] = acc00[r] + bs0;
    out[m0*512 + c1] = acc01[r] + bs1;
    out[m1*512 + c0] = acc10[r] + bs0;
    out[m1*512 + c1] = acc11[r] + bs1;
  }
}

// ---------------- Kernel 2: the recurrence (single-WG-resident W_hh) ----------------
__global__ __launch_bounds__(512, 2) void k_rnn(
    const float* __restrict__ Whh,
    float* __restrict__ out)
{
  const int b   = blockIdx.x;      // pair id 0..31 -> batch rows {2b, 2b+1}
  const int tid = threadIdx.x;
  const int w   = tid >> 6;        // wave 0..7 owns cols [64w, 64w+64)
  const int l   = tid & 63;
  const int lr  = l & 15;          // A-row / D-col index within 16-tile
  const int kg  = l >> 4;          // k-group
  const int wc0 = w * 64;

  // LDS: W col-tile 3 as pre-formatted A-frags (per-wave private region), h double-buffer
  __shared__ _Float16 wlds[8][16][512];   // [wave][kstep][lane*8] = 128 KB
  __shared__ _Float16 hbuf[2][2][520];    // [buf][j][k], padded row = 1040 B

  for (int i = tid; i < 2*2*520; i += 512) (&hbuf[0][0][0])[i] = (_Float16)0.0f;

  // Load W_hh. A-frag for col-tile ct: row i = lr -> global col c = wc0+16ct+lr,
  // k = 32*ks + 8*kg + e. Col-tiles 0..2 -> VGPR/AGPR, tile 3 -> LDS.
  half8 Wv[3][16];
  #pragma unroll
  for (int ct = 0; ct < 3; ++ct){
    #pragma unroll
    for (int ks = 0; ks < 16; ++ks){
      Wv[ct][ks] = cvt8(Whh + (long long)(wc0 + ct*16 + lr)*512 + ks*32 + kg*8);
    }
  }
  #pragma unroll
  for (int ks = 0; ks < 16; ++ks){
    half8 v = cvt8(Whh + (long long)(wc0 + 48 + lr)*512 + ks*32 + kg*8);
    *(half8*)&wlds[w][ks][l*8] = v;
  }
  __syncthreads();

  const int jj = l & 1;                 // h row fed to this lane's B-column
  const long long nb = (long long)(b*2 + (lr < 2 ? lr : 0)) * 2048 * 512;

  for (int t = 0; t < 2048; ++t){
    const int bufc = t & 1, bufp = bufc ^ 1;

    // prefetch xh' (K1 wrote it into d_out at the slot we will overwrite with h_t)
    f32x4 xh0 = {0,0,0,0}, xh1 = {0,0,0,0}, xh2 = {0,0,0,0}, xh3 = {0,0,0,0};
    long long ob = 0;
    const bool act = (lr < 2);
    if (act){
      ob = nb + (long long)t*512 + wc0 + kg*4;
      xh0 = *(const f32x4*)(out + ob);
      xh1 = *(const f32x4*)(out + ob + 16);
      xh2 = *(const f32x4*)(out + ob + 32);
      xh3 = *(const f32x4*)(out + ob + 48);
    }

    f32x4 acc0 = {0,0,0,0}, acc1 = {0,0,0,0}, acc2 = {0,0,0,0}, acc3 = {0,0,0,0};

    #pragma unroll
    for (int ks = 0; ks < 16; ++ks){
      half8 hf = *(const half8*)&hbuf[bufp][jj][ks*32 + kg*8];
      half8 w3 = *(const half8*)&wlds[w][ks][l*8];
      acc0 = MFMA_F16(Wv[0][ks], hf, acc0);
      acc1 = MFMA_F16(Wv[1][ks], hf, acc1);
      acc2 = MFMA_F16(Wv[2][ks], hf, acc2);
      acc3 = MFMA_F16(w3, hf, acc3);
    }

    // epilogue: lanes with lr<2 hold D cols j=lr (batch), rows i=4kg+r (output col)
    if (act){
      f32x4 h0, h1, h2, h3;
      #pragma unroll
      for (int r = 0; r < 4; ++r){
        h0[r] = tanh_fast(acc0[r] + xh0[r]);
        h1[r] = tanh_fast(acc1[r] + xh1[r]);
        h2[r] = tanh_fast(acc2[r] + xh2[r]);
        h3[r] = tanh_fast(acc3[r] + xh3[r]);
      }
      *(f32x4*)(out + ob)      = h0;
      *(f32x4*)(out + ob + 16) = h1;
      *(f32x4*)(out + ob + 32) = h2;
      *(f32x4*)(out + ob + 48) = h3;

      union { _Float16 h[4]; unsigned long long u; } p0, p1, p2, p3;
      #pragma unroll
      for (int r = 0; r < 4; ++r){
        p0.h[r] = (_Float16)h0[r]; p1.h[r] = (_Float16)h1[r];
        p2.h[r] = (_Float16)h2[r]; p3.h[r] = (_Float16)h3[r];
      }
      const int cl = wc0 + kg*4;
      *(unsigned long long*)&hbuf[bufc][lr][cl]      = p0.u;
      *(unsigned long long*)&hbuf[bufc][lr][cl + 16] = p1.u;
      *(unsigned long long*)&hbuf[bufc][lr][cl + 32] = p2.u;
      *(unsigned long long*)&hbuf[bufc][lr][cl + 48] = p3.u;
    }

    __syncthreads();
  }
}

extern "C" void kernel_launch(void* const* d_in, const int* in_sizes, int n_in,
                              void* d_out, int out_size, void* d_ws, size_t ws_size,
                              hipStream_t stream)
{
  const int*   X    = (const int*)  d_in[0];
  const float* emb  = (const float*)d_in[1];
  const float* Whh  = (const float*)d_in[2];
  const float* bhh  = (const float*)d_in[3];
  const float* Wxh  = (const float*)d_in[4];
  const float* bxh  = (const float*)d_in[5];
  float* out = (float*)d_out;

  hipLaunchKernelGGL(k_xh,  dim3(16384), dim3(256), 0, stream, X, emb, Wxh, bxh, bhh, out);
  hipLaunchKernelGGL(k_rnn, dim3(32),    dim3(512), 0, stream, Whh, out);
}